// Round 5
// baseline (696.359 us; speedup 1.0000x reference)
//
#include <hip/hip_runtime.h>
#include <math.h>

#define H 1024
#define NHEAD 16
#define HDIM 64
#define IDIM 4096
#define BATCH 4
#define SEQ 2048
#define NTOK 8192
#define LN_EPS 1e-5f

typedef __bf16 bf16x8 __attribute__((ext_vector_type(8)));
typedef __bf16 bf16x4 __attribute__((ext_vector_type(4)));
typedef float f32x4 __attribute__((ext_vector_type(4)));
typedef unsigned short ushort8 __attribute__((ext_vector_type(8)));
typedef unsigned short ushort4v __attribute__((ext_vector_type(4)));

__device__ __forceinline__ unsigned short f2bf(float f) {
  union { float f; unsigned int u; } v; v.f = f;
  unsigned int u = v.u;
  return (unsigned short)((u + 0x7FFFu + ((u >> 16) & 1u)) >> 16);
}

// ---------- transpose + cast: W[K][N] f32 -> Wt[N][K] bf16 ----------
__global__ void transpose_cast_kernel(const float* __restrict__ W,
                                      unsigned short* __restrict__ Wt,
                                      int K, int N) {
  __shared__ unsigned short tile[32][33];
  int n0 = blockIdx.x * 32, k0 = blockIdx.y * 32;
  int tx = threadIdx.x, ty = threadIdx.y;  // 32 x 8
#pragma unroll
  for (int i = 0; i < 4; i++) {
    int k = ty + i * 8;
    tile[tx][k] = f2bf(W[(size_t)(k0 + k) * N + n0 + tx]);
  }
  __syncthreads();
#pragma unroll
  for (int i = 0; i < 4; i++) {
    int n = ty + i * 8;
    Wt[(size_t)(n0 + n) * K + k0 + tx] = tile[n][tx];
  }
}

// ---------- transpose V slice of qkv: bf16 [NTOK][3H] -> vt[bh][d][s] ----------
__global__ void transpose_v_kernel(const unsigned short* __restrict__ qkv,
                                   unsigned short* __restrict__ vt) {
  __shared__ unsigned short tile[32][33];
  int s0 = blockIdx.x * 32, d0 = blockIdx.y * 32;
  int bh = blockIdx.z, b = bh >> 4, h = bh & 15;
  int tx = threadIdx.x, ty = threadIdx.y;  // 32 x 8
#pragma unroll
  for (int i = 0; i < 4; i++) {
    int s = ty + i * 8;
    tile[s][tx] = qkv[((size_t)b * SEQ + s0 + s) * (3 * H) + 2 * H + h * HDIM + d0 + tx];
  }
  __syncthreads();
#pragma unroll
  for (int i = 0; i < 4; i++) {
    int d = ty + i * 8;
    vt[((size_t)bh * HDIM + d0 + d) * SEQ + s0 + tx] = tile[tx][d];
  }
}

// ---------- layernorm: f32 [rows][H] -> bf16 ----------
__global__ __launch_bounds__(256)
void layernorm_kernel(const float* __restrict__ x, const float* __restrict__ g,
                      const float* __restrict__ b, unsigned short* __restrict__ out) {
  __shared__ float sb[4];
  int row = blockIdx.x;
  int tid = threadIdx.x;
  const float4* xr = (const float4*)(x + (size_t)row * H);
  float4 v = xr[tid];
  float s = v.x + v.y + v.z + v.w;
#pragma unroll
  for (int o = 32; o > 0; o >>= 1) s += __shfl_down(s, o);
  if ((tid & 63) == 0) sb[tid >> 6] = s;
  __syncthreads();
  float mu = (sb[0] + sb[1] + sb[2] + sb[3]) * (1.0f / H);
  __syncthreads();
  float dx = v.x - mu, dy = v.y - mu, dz = v.z - mu, dw = v.w - mu;
  float s2 = dx * dx + dy * dy + dz * dz + dw * dw;
#pragma unroll
  for (int o = 32; o > 0; o >>= 1) s2 += __shfl_down(s2, o);
  if ((tid & 63) == 0) sb[tid >> 6] = s2;
  __syncthreads();
  float var = (sb[0] + sb[1] + sb[2] + sb[3]) * (1.0f / H);
  float rs = rsqrtf(var + LN_EPS);
  float4 gv = ((const float4*)g)[tid];
  float4 bv = ((const float4*)b)[tid];
  ushort4v ov;
  ov[0] = f2bf(dx * rs * gv.x + bv.x);
  ov[1] = f2bf(dy * rs * gv.y + bv.y);
  ov[2] = f2bf(dz * rs * gv.z + bv.z);
  ov[3] = f2bf(dw * rs * gv.w + bv.w);
  ((ushort4v*)(out + (size_t)row * H))[tid] = ov;
}

// ---------- GEMM: C = A(bf16,[M][K]) @ Bt(bf16,[N][K])^T + bias ----------
// K-loop = m97 structure (global_load_lds w16, XOR source swizzle, unpadded LDS).
// MFMA computes C^T (a=B frag, b=A frag): lane owns row m=l16, reg r = 4
// consecutive N cols -> packed b64 bf16 / float4 f32 epilogue stores.
// EPI 0: bf16; 1: bf16 gelu (sigmoid form); 2: f32 + residual.
template <int EPI>
__global__ __launch_bounds__(256)
void gemm_bt_kernel(const unsigned short* __restrict__ A,
                    const unsigned short* __restrict__ Bt,
                    const float* __restrict__ bias,
                    const float* __restrict__ res,
                    void* __restrict__ out, int M, int N, int K) {
  __shared__ __align__(16) unsigned short As[128 * 32];
  __shared__ __align__(16) unsigned short Bs[128 * 32];
  int tid = threadIdx.x;
  int wave = tid >> 6, lane = tid & 63;
  int quad = lane >> 4, l16 = lane & 15;
  int wm = wave >> 1, wn = wave & 1;
  int m0 = blockIdx.y * 128, n0 = blockIdx.x * 128;
  f32x4 acc[4][4];  // [i=m strip][j=n strip]; reg r = n offset (C^T layout)
#pragma unroll
  for (int i = 0; i < 4; i++)
#pragma unroll
    for (int j = 0; j < 4; j++) acc[i][j] = (f32x4){0.f, 0.f, 0.f, 0.f};

  int rl = (lane >> 2);
  int cphys = lane & 3;
  for (int k0 = 0; k0 < K; k0 += 32) {
    __syncthreads();
#pragma unroll
    for (int t = 0; t < 2; t++) {
      int ch = wave * 2 + t;
      int rloc = ch * 16 + rl;
      int clog = cphys ^ ((rloc >> 1) & 3);
      const unsigned short* ga = A + (size_t)(m0 + rloc) * K + k0 + clog * 8;
      __builtin_amdgcn_global_load_lds(
          (const __attribute__((address_space(1))) unsigned int*)ga,
          (__attribute__((address_space(3))) unsigned int*)(As + ch * 512), 16, 0, 0);
      const unsigned short* gb = Bt + (size_t)(n0 + rloc) * K + k0 + clog * 8;
      __builtin_amdgcn_global_load_lds(
          (const __attribute__((address_space(1))) unsigned int*)gb,
          (__attribute__((address_space(3))) unsigned int*)(Bs + ch * 512), 16, 0, 0);
    }
    __syncthreads();
    bf16x8 af[4], bfv[4];
#pragma unroll
    for (int i = 0; i < 4; i++) {
      int ra = wm * 64 + i * 16 + l16;
      af[i] = *(const bf16x8*)&As[ra * 32 + ((quad ^ ((ra >> 1) & 3)) << 3)];
      int rb = wn * 64 + i * 16 + l16;
      bfv[i] = *(const bf16x8*)&Bs[rb * 32 + ((quad ^ ((rb >> 1) & 3)) << 3)];
    }
#pragma unroll
    for (int i = 0; i < 4; i++)
#pragma unroll
      for (int j = 0; j < 4; j++)
        acc[i][j] = __builtin_amdgcn_mfma_f32_16x16x32_bf16(bfv[j], af[i], acc[i][j], 0, 0, 0);
  }
  // epilogue: lane = row m (l16), reg r = col n offset (quad*4+r), packed stores
#pragma unroll
  for (int i = 0; i < 4; i++) {
    int m = m0 + wm * 64 + i * 16 + l16;
#pragma unroll
    for (int j = 0; j < 4; j++) {
      int nb = n0 + wn * 64 + j * 16 + quad * 4;
      float4 bv4 = *(const float4*)&bias[nb];
      float v0 = acc[i][j][0] + bv4.x;
      float v1 = acc[i][j][1] + bv4.y;
      float v2 = acc[i][j][2] + bv4.z;
      float v3 = acc[i][j][3] + bv4.w;
      size_t off = (size_t)m * N + nb;
      if (EPI == 0) {
        bf16x4 pk = {(__bf16)v0, (__bf16)v1, (__bf16)v2, (__bf16)v3};
        *(bf16x4*)&((unsigned short*)out)[off] = pk;
      } else if (EPI == 1) {
        // gelu(v) = v * sigmoid(1.5957691*(v + 0.044715 v^3))
        float g0 = v0 / (1.f + __expf(-1.5957691216057308f * (v0 + 0.044715f * v0 * v0 * v0)));
        float g1 = v1 / (1.f + __expf(-1.5957691216057308f * (v1 + 0.044715f * v1 * v1 * v1)));
        float g2 = v2 / (1.f + __expf(-1.5957691216057308f * (v2 + 0.044715f * v2 * v2 * v2)));
        float g3 = v3 / (1.f + __expf(-1.5957691216057308f * (v3 + 0.044715f * v3 * v3 * v3)));
        bf16x4 pk = {(__bf16)g0, (__bf16)g1, (__bf16)g2, (__bf16)g3};
        *(bf16x4*)&((unsigned short*)out)[off] = pk;
      } else {
        float4 rv = *(const float4*)&res[off];
        float4 o4;
        o4.x = v0 + rv.x; o4.y = v1 + rv.y; o4.z = v2 + rv.z; o4.w = v3 + rv.w;
        *(float4*)&((float*)out)[off] = o4;
      }
    }
  }
}

// ---------- flash attention v5 ----------
// Block = 4 waves, BQ=128 (wave owns 32 q rows), BKV=64, grid 16x64=1024 blocks.
// K staged to LDS via global_load_lds (XOR source swizzle). V fragments
// register-prefetched from vt before the staging barrier. S^T = mfma(K_a, Q_b)
// -> P exits kv-contiguous -> packed ds_write_b64; O^T = mfma(V_a, P_b) ->
// lane-local inv-l scale, 8B packed stores. Max-free softmax (|s/8| << 88).
__global__ __launch_bounds__(256)
void flash_attn_kernel(const unsigned short* __restrict__ qkv,
                       const unsigned short* __restrict__ vt,
                       unsigned short* __restrict__ attn_out) {
  constexpr int LPs = 72;  // 144B stride: frag ops land 2-way on banks (free)
  __shared__ __align__(16) unsigned short Ks[64 * 64];
  __shared__ __align__(16) unsigned short Ps[4 * 32 * LPs];
  int tid = threadIdx.x;
  int wave = tid >> 6, lane = tid & 63;
  int quad = lane >> 4, l16 = lane & 15;
  int bh = blockIdx.y, b = bh >> 4, h = bh & 15;
  int qblk = blockIdx.x * 128 + wave * 32;
  const size_t qrow = 3 * H;
  const size_t tok0 = (size_t)b * SEQ;
  const size_t vbase = (size_t)bh * HDIM * SEQ;
  unsigned short* Psw = Ps + wave * 32 * LPs;

  // Q B-fragments (q on l16), register-resident for the whole loop
  bf16x8 qb[2][2];
#pragma unroll
  for (int mb = 0; mb < 2; mb++)
#pragma unroll
    for (int ks = 0; ks < 2; ks++)
      qb[mb][ks] = *(const bf16x8*)&qkv[(tok0 + qblk + mb * 16 + l16) * qrow +
                                        h * HDIM + ks * 32 + quad * 8];

  float l_part[2] = {0.f, 0.f};
  f32x4 o_acc[2][4];  // [mb][db], O^T layout (rows d, cols q)
#pragma unroll
  for (int mb = 0; mb < 2; mb++)
#pragma unroll
    for (int db = 0; db < 4; db++) o_acc[mb][db] = (f32x4){0.f, 0.f, 0.f, 0.f};

  int srow = lane >> 3;            // 0..7: row within 8-row staging group
  int schunk = (lane & 7) ^ srow;  // swizzled 16B source chunk

  for (int kv0 = 0; kv0 < SEQ; kv0 += 64) {
    __syncthreads();  // prev-iter Ks reads complete before restaging
#pragma unroll
    for (int t = 0; t < 2; t++) {
      int rbase = wave * 16 + t * 8;
      const unsigned short* ga =
          &qkv[(tok0 + kv0 + rbase + srow) * qrow + H + h * HDIM + schunk * 8];
      __builtin_amdgcn_global_load_lds(
          (const __attribute__((address_space(1))) unsigned int*)ga,
          (__attribute__((address_space(3))) unsigned int*)(Ks + rbase * 64), 16, 0, 0);
    }
    // V A-fragments (global prefetch; staging barrier's vmcnt(0) is the wait)
    bf16x8 va[4][2];
#pragma unroll
    for (int db = 0; db < 4; db++)
#pragma unroll
      for (int ks = 0; ks < 2; ks++)
        va[db][ks] = *(const bf16x8*)&vt[vbase + (size_t)(db * 16 + l16) * SEQ +
                                         kv0 + ks * 32 + quad * 8];
    __syncthreads();  // Ks visible (+ va in regs)
    // S^T[kv][q] = K . Q^T, one 16-kv strip (nb) at a time
#pragma unroll
    for (int nb = 0; nb < 4; nb++) {
      int row = nb * 16 + l16;
      bf16x8 ka[2];
#pragma unroll
      for (int ks = 0; ks < 2; ks++) {
        int pc = (ks * 4 + quad) ^ (row & 7);
        ka[ks] = *(const bf16x8*)&Ks[row * 64 + pc * 8];
      }
      f32x4 st[2];
#pragma unroll
      for (int mb = 0; mb < 2; mb++) st[mb] = (f32x4){0.f, 0.f, 0.f, 0.f};
#pragma unroll
      for (int ks = 0; ks < 2; ks++)
#pragma unroll
        for (int mb = 0; mb < 2; mb++)
          st[mb] = __builtin_amdgcn_mfma_f32_16x16x32_bf16(ka[ks], qb[mb][ks], st[mb], 0, 0, 0);
      // p = exp(s/8); lane holds kv = nb*16+quad*4+r (contig), q = mb*16+l16
#pragma unroll
      for (int mb = 0; mb < 2; mb++) {
        float p0 = __expf(st[mb][0] * 0.125f);
        float p1 = __expf(st[mb][1] * 0.125f);
        float p2 = __expf(st[mb][2] * 0.125f);
        float p3 = __expf(st[mb][3] * 0.125f);
        l_part[mb] += (p0 + p1) + (p2 + p3);
        bf16x4 pk = {(__bf16)p0, (__bf16)p1, (__bf16)p2, (__bf16)p3};
        *(bf16x4*)&Psw[(mb * 16 + l16) * LPs + nb * 16 + quad * 4] = pk;
      }
    }
    // Ps is wave-private: drain own ds_writes, no barrier
    __asm__ volatile("s_waitcnt lgkmcnt(0)" ::: "memory");
    // O^T += V^T P^T : a = V rows (d, kv-contig), b = P rows (q, kv-contig)
#pragma unroll
    for (int ks = 0; ks < 2; ks++) {
      bf16x8 pb[2];
#pragma unroll
      for (int mb = 0; mb < 2; mb++)
        pb[mb] = *(const bf16x8*)&Psw[(mb * 16 + l16) * LPs + ks * 32 + quad * 8];
#pragma unroll
      for (int db = 0; db < 4; db++)
#pragma unroll
        for (int mb = 0; mb < 2; mb++)
          o_acc[mb][db] = __builtin_amdgcn_mfma_f32_16x16x32_bf16(va[db][ks], pb[mb],
                                                                  o_acc[mb][db], 0, 0, 0);
    }
  }
  // reduce l across the 4 quads; lane then holds inv-l for its own q = mb*16+l16
#pragma unroll
  for (int mb = 0; mb < 2; mb++) {
    l_part[mb] += __shfl_xor(l_part[mb], 16);
    l_part[mb] += __shfl_xor(l_part[mb], 32);
    l_part[mb] = 1.0f / l_part[mb];
  }
  // O^T C-layout: col q = mb*16+l16, rows d = db*16+quad*4+r (contig) -> 8B stores
#pragma unroll
  for (int mb = 0; mb < 2; mb++) {
#pragma unroll
    for (int db = 0; db < 4; db++) {
      ushort4v o;
#pragma unroll
      for (int r = 0; r < 4; r++) o[r] = f2bf(o_acc[mb][db][r] * l_part[mb]);
      *(ushort4v*)&attn_out[(tok0 + qblk + mb * 16 + l16) * H + h * HDIM +
                            db * 16 + quad * 4] = o;
    }
  }
}

extern "C" void kernel_launch(void* const* d_in, const int* in_sizes, int n_in,
                              void* d_out, int out_size, void* d_ws, size_t ws_size,
                              hipStream_t stream) {
  const float* x = (const float*)d_in[0];
  const float* ln1_g = (const float*)d_in[1];
  const float* ln1_b = (const float*)d_in[2];
  const float* qkv_w = (const float*)d_in[3];
  const float* qkv_b = (const float*)d_in[4];
  const float* out_w = (const float*)d_in[5];
  const float* out_b = (const float*)d_in[6];
  const float* ln2_g = (const float*)d_in[7];
  const float* ln2_b = (const float*)d_in[8];
  const float* w1 = (const float*)d_in[9];
  const float* b1 = (const float*)d_in[10];
  const float* w2 = (const float*)d_in[11];
  const float* b2 = (const float*)d_in[12];
  float* outp = (float*)d_out;

  size_t off = 0;
  auto take = [&](size_t n) {
    char* p = (char*)d_ws + off;
    off += (n + 255) & ~(size_t)255;
    return p;
  };
  unsigned short* h1 = (unsigned short*)take((size_t)NTOK * H * 2);       // also h2
  unsigned short* qkvb = (unsigned short*)take((size_t)NTOK * 3 * H * 2); // qkv; later mid
  unsigned short* attn = (unsigned short*)take((size_t)NTOK * H * 2);
  float* x1 = (float*)take((size_t)NTOK * H * 4);
  unsigned short* qkvwt = (unsigned short*)take((size_t)3 * H * H * 2);
  unsigned short* outwt = (unsigned short*)take((size_t)H * H * 2);
  unsigned short* w1t = (unsigned short*)take((size_t)H * IDIM * 2);
  unsigned short* w2t = (unsigned short*)take((size_t)H * IDIM * 2);
  unsigned short* h2 = h1;
  unsigned short* mid = qkvb;                // [NTOK][IDIM] aliases qkv+attn exactly
  unsigned short* vt = (unsigned short*)x1;  // vt dead before proj writes x1

  dim3 tb(32, 8);
  transpose_cast_kernel<<<dim3(3 * H / 32, H / 32), tb, 0, stream>>>(qkv_w, qkvwt, H, 3 * H);
  transpose_cast_kernel<<<dim3(H / 32, H / 32), tb, 0, stream>>>(out_w, outwt, H, H);
  transpose_cast_kernel<<<dim3(IDIM / 32, H / 32), tb, 0, stream>>>(w1, w1t, H, IDIM);
  transpose_cast_kernel<<<dim3(H / 32, IDIM / 32), tb, 0, stream>>>(w2, w2t, IDIM, H);

  layernorm_kernel<<<NTOK, 256, 0, stream>>>(x, ln1_g, ln1_b, h1);
  gemm_bt_kernel<0><<<dim3(3 * H / 128, NTOK / 128), 256, 0, stream>>>(
      h1, qkvwt, qkv_b, nullptr, qkvb, NTOK, 3 * H, H);
  transpose_v_kernel<<<dim3(SEQ / 32, HDIM / 32, BATCH * NHEAD), tb, 0, stream>>>(qkvb, vt);
  flash_attn_kernel<<<dim3(SEQ / 128, BATCH * NHEAD), 256, 0, stream>>>(qkvb, vt, attn);
  gemm_bt_kernel<2><<<dim3(H / 128, NTOK / 128), 256, 0, stream>>>(
      attn, outwt, out_b, x, x1, NTOK, H, H);
  layernorm_kernel<<<NTOK, 256, 0, stream>>>(x1, ln2_g, ln2_b, h2);
  gemm_bt_kernel<1><<<dim3(IDIM / 128, NTOK / 128), 256, 0, stream>>>(
      h2, w1t, b1, nullptr, mid, NTOK, IDIM, H);
  gemm_bt_kernel<2><<<dim3(H / 128, NTOK / 128), 256, 0, stream>>>(
      mid, w2t, b2, x1, outp, NTOK, H, IDIM);
}

// Round 6
// 685.968 us; speedup vs baseline: 1.0151x; 1.0151x over previous
//
#include <hip/hip_runtime.h>
#include <math.h>

#define H 1024
#define NHEAD 16
#define HDIM 64
#define IDIM 4096
#define BATCH 4
#define SEQ 2048
#define NTOK 8192
#define LN_EPS 1e-5f

typedef __bf16 bf16x8 __attribute__((ext_vector_type(8)));
typedef __bf16 bf16x4 __attribute__((ext_vector_type(4)));
typedef float f32x4 __attribute__((ext_vector_type(4)));
typedef unsigned short ushort8 __attribute__((ext_vector_type(8)));
typedef unsigned short ushort4v __attribute__((ext_vector_type(4)));

__device__ __forceinline__ unsigned short f2bf(float f) {
  union { float f; unsigned int u; } v; v.f = f;
  unsigned int u = v.u;
  return (unsigned short)((u + 0x7FFFu + ((u >> 16) & 1u)) >> 16);
}

// ---------- transpose + cast: W[K][N] f32 -> Wt[N][K] bf16 ----------
__global__ void transpose_cast_kernel(const float* __restrict__ W,
                                      unsigned short* __restrict__ Wt,
                                      int K, int N) {
  __shared__ unsigned short tile[32][33];
  int n0 = blockIdx.x * 32, k0 = blockIdx.y * 32;
  int tx = threadIdx.x, ty = threadIdx.y;  // 32 x 8
#pragma unroll
  for (int i = 0; i < 4; i++) {
    int k = ty + i * 8;
    tile[tx][k] = f2bf(W[(size_t)(k0 + k) * N + n0 + tx]);
  }
  __syncthreads();
#pragma unroll
  for (int i = 0; i < 4; i++) {
    int n = ty + i * 8;
    Wt[(size_t)(n0 + n) * K + k0 + tx] = tile[n][tx];
  }
}

// ---------- layernorm: f32 [rows][H] -> bf16 ----------
__global__ __launch_bounds__(256)
void layernorm_kernel(const float* __restrict__ x, const float* __restrict__ g,
                      const float* __restrict__ b, unsigned short* __restrict__ out) {
  __shared__ float sb[4];
  int row = blockIdx.x;
  int tid = threadIdx.x;
  const float4* xr = (const float4*)(x + (size_t)row * H);
  float4 v = xr[tid];
  float s = v.x + v.y + v.z + v.w;
#pragma unroll
  for (int o = 32; o > 0; o >>= 1) s += __shfl_down(s, o);
  if ((tid & 63) == 0) sb[tid >> 6] = s;
  __syncthreads();
  float mu = (sb[0] + sb[1] + sb[2] + sb[3]) * (1.0f / H);
  __syncthreads();
  float dx = v.x - mu, dy = v.y - mu, dz = v.z - mu, dw = v.w - mu;
  float s2 = dx * dx + dy * dy + dz * dz + dw * dw;
#pragma unroll
  for (int o = 32; o > 0; o >>= 1) s2 += __shfl_down(s2, o);
  if ((tid & 63) == 0) sb[tid >> 6] = s2;
  __syncthreads();
  float var = (sb[0] + sb[1] + sb[2] + sb[3]) * (1.0f / H);
  float rs = rsqrtf(var + LN_EPS);
  float4 gv = ((const float4*)g)[tid];
  float4 bv = ((const float4*)b)[tid];
  ushort4v ov;
  ov[0] = f2bf(dx * rs * gv.x + bv.x);
  ov[1] = f2bf(dy * rs * gv.y + bv.y);
  ov[2] = f2bf(dz * rs * gv.z + bv.z);
  ov[3] = f2bf(dw * rs * gv.w + bv.w);
  ((ushort4v*)(out + (size_t)row * H))[tid] = ov;
}

// ---------- GEMM: C = A(bf16,[M][K]) @ Bt(bf16,[N][K])^T + bias ----------
// K-loop = m97 structure. MFMA computes C^T (lane owns row m=l16, reg r = 4
// consecutive N cols). EPI 0: bf16 (with optional fused V-transpose for QKV's
// v-slice blocks: n0>=2H writes vt[bh][d][s] instead of qkvb); 1: bf16 gelu;
// 2: f32 + residual.
template <int EPI>
__global__ __launch_bounds__(256)
void gemm_bt_kernel(const unsigned short* __restrict__ A,
                    const unsigned short* __restrict__ Bt,
                    const float* __restrict__ bias,
                    const float* __restrict__ res,
                    void* __restrict__ out, unsigned short* __restrict__ vt_out,
                    int M, int N, int K) {
  __shared__ __align__(16) unsigned short As[128 * 32];
  __shared__ __align__(16) unsigned short Bs[128 * 32];
  int tid = threadIdx.x;
  int wave = tid >> 6, lane = tid & 63;
  int quad = lane >> 4, l16 = lane & 15;
  int wm = wave >> 1, wn = wave & 1;
  int m0 = blockIdx.y * 128, n0 = blockIdx.x * 128;
  f32x4 acc[4][4];  // [i=m strip][j=n strip]; reg r = n offset (C^T layout)
#pragma unroll
  for (int i = 0; i < 4; i++)
#pragma unroll
    for (int j = 0; j < 4; j++) acc[i][j] = (f32x4){0.f, 0.f, 0.f, 0.f};

  int rl = (lane >> 2);
  int cphys = lane & 3;
  for (int k0 = 0; k0 < K; k0 += 32) {
    __syncthreads();
#pragma unroll
    for (int t = 0; t < 2; t++) {
      int ch = wave * 2 + t;
      int rloc = ch * 16 + rl;
      int clog = cphys ^ ((rloc >> 1) & 3);
      const unsigned short* ga = A + (size_t)(m0 + rloc) * K + k0 + clog * 8;
      __builtin_amdgcn_global_load_lds(
          (const __attribute__((address_space(1))) unsigned int*)ga,
          (__attribute__((address_space(3))) unsigned int*)(As + ch * 512), 16, 0, 0);
      const unsigned short* gb = Bt + (size_t)(n0 + rloc) * K + k0 + clog * 8;
      __builtin_amdgcn_global_load_lds(
          (const __attribute__((address_space(1))) unsigned int*)gb,
          (__attribute__((address_space(3))) unsigned int*)(Bs + ch * 512), 16, 0, 0);
    }
    __syncthreads();
    bf16x8 af[4], bfv[4];
#pragma unroll
    for (int i = 0; i < 4; i++) {
      int ra = wm * 64 + i * 16 + l16;
      af[i] = *(const bf16x8*)&As[ra * 32 + ((quad ^ ((ra >> 1) & 3)) << 3)];
      int rb = wn * 64 + i * 16 + l16;
      bfv[i] = *(const bf16x8*)&Bs[rb * 32 + ((quad ^ ((rb >> 1) & 3)) << 3)];
    }
#pragma unroll
    for (int i = 0; i < 4; i++)
#pragma unroll
      for (int j = 0; j < 4; j++)
        acc[i][j] = __builtin_amdgcn_mfma_f32_16x16x32_bf16(bfv[j], af[i], acc[i][j], 0, 0, 0);
  }
  // epilogue: lane = row m (l16), reg r = col n offset (quad*4+r)
  bool vslice = (EPI == 0) && (vt_out != nullptr) && (n0 >= 2 * H);
#pragma unroll
  for (int i = 0; i < 4; i++) {
    int m = m0 + wm * 64 + i * 16 + l16;
#pragma unroll
    for (int j = 0; j < 4; j++) {
      int nb = n0 + wn * 64 + j * 16 + quad * 4;
      float4 bv4 = *(const float4*)&bias[nb];
      float v0 = acc[i][j][0] + bv4.x;
      float v1 = acc[i][j][1] + bv4.y;
      float v2 = acc[i][j][2] + bv4.z;
      float v3 = acc[i][j][3] + bv4.w;
      size_t off = (size_t)m * N + nb;
      if (EPI == 0) {
        if (vslice) {
          // write vt[bh][d][s] transposed; skip the qkvb row write
          int bb = m >> 11, s = m & (SEQ - 1);
          int cb = nb - 2 * H;
          int hh = cb >> 6, dd = cb & 63;
          size_t base = ((size_t)(bb * NHEAD + hh) * HDIM + dd) * SEQ + s;
          vt_out[base] = f2bf(v0);
          vt_out[base + SEQ] = f2bf(v1);
          vt_out[base + 2 * SEQ] = f2bf(v2);
          vt_out[base + 3 * SEQ] = f2bf(v3);
        } else {
          bf16x4 pk = {(__bf16)v0, (__bf16)v1, (__bf16)v2, (__bf16)v3};
          *(bf16x4*)&((unsigned short*)out)[off] = pk;
        }
      } else if (EPI == 1) {
        float g0 = v0 / (1.f + __expf(-1.5957691216057308f * (v0 + 0.044715f * v0 * v0 * v0)));
        float g1 = v1 / (1.f + __expf(-1.5957691216057308f * (v1 + 0.044715f * v1 * v1 * v1)));
        float g2 = v2 / (1.f + __expf(-1.5957691216057308f * (v2 + 0.044715f * v2 * v2 * v2)));
        float g3 = v3 / (1.f + __expf(-1.5957691216057308f * (v3 + 0.044715f * v3 * v3 * v3)));
        bf16x4 pk = {(__bf16)g0, (__bf16)g1, (__bf16)g2, (__bf16)g3};
        *(bf16x4*)&((unsigned short*)out)[off] = pk;
      } else {
        float4 rv = *(const float4*)&res[off];
        float4 o4;
        o4.x = v0 + rv.x; o4.y = v1 + rv.y; o4.z = v2 + rv.z; o4.w = v3 + rv.w;
        *(float4*)&((float*)out)[off] = o4;
      }
    }
  }
}

// ---------- flash attention v6: single-barrier pipelined K staging ----------
// Block = 4 waves, BQ=128 (wave owns 32 q), BKV=64, grid 1024 blocks.
// Ks double-buffered: next tile's global_load_lds issued right after the single
// per-iter __syncthreads (whose implicit vmcnt(0) drain is the *next* iter's
// wait -> loads get a full compute phase to land). va (V register frags) are
// issued BEFORE the stage so PV's vmcnt wait leaves the prefetch in flight.
// S^T = mfma(K_a, Q_b); P kv-contig -> packed ds_write_b64; PV split per
// 32-kv half with partial lgkm drains. Max-free softmax (|s/8| << 88).
__global__ __launch_bounds__(256)
void flash_attn_kernel(const unsigned short* __restrict__ qkv,
                       const unsigned short* __restrict__ vt,
                       unsigned short* __restrict__ attn_out) {
  constexpr int LPs = 72;
  __shared__ __align__(16) unsigned short Ks[2][64 * 64];
  __shared__ __align__(16) unsigned short Ps[4 * 32 * LPs];
  int tid = threadIdx.x;
  int wave = tid >> 6, lane = tid & 63;
  int quad = lane >> 4, l16 = lane & 15;
  int bh = blockIdx.y, b = bh >> 4, h = bh & 15;
  int qblk = blockIdx.x * 128 + wave * 32;
  const size_t qrow = 3 * H;
  const size_t tok0 = (size_t)b * SEQ;
  const size_t vbase = (size_t)bh * HDIM * SEQ;
  unsigned short* Psw = Ps + wave * 32 * LPs;

  // Q B-fragments (q on l16), register-resident for the whole loop
  bf16x8 qb[2][2];
#pragma unroll
  for (int mb = 0; mb < 2; mb++)
#pragma unroll
    for (int ks = 0; ks < 2; ks++)
      qb[mb][ks] = *(const bf16x8*)&qkv[(tok0 + qblk + mb * 16 + l16) * qrow +
                                        h * HDIM + ks * 32 + quad * 8];

  float l_part[2] = {0.f, 0.f};
  f32x4 o_acc[2][4];  // [mb][db], O^T layout (rows d, cols q)
#pragma unroll
  for (int mb = 0; mb < 2; mb++)
#pragma unroll
    for (int db = 0; db < 4; db++) o_acc[mb][db] = (f32x4){0.f, 0.f, 0.f, 0.f};

  int srow = lane >> 3;            // 0..7: row within 8-row staging group
  int schunk = (lane & 7) ^ srow;  // swizzled 16B source chunk

  // prologue: stage tile 0 into buf 0
#pragma unroll
  for (int t = 0; t < 2; t++) {
    int rbase = wave * 16 + t * 8;
    const unsigned short* ga =
        &qkv[(tok0 + rbase + srow) * qrow + H + h * HDIM + schunk * 8];
    __builtin_amdgcn_global_load_lds(
        (const __attribute__((address_space(1))) unsigned int*)ga,
        (__attribute__((address_space(3))) unsigned int*)(&Ks[0][rbase * 64]), 16, 0, 0);
  }

  for (int kv0 = 0; kv0 < SEQ; kv0 += 64) {
    int buf = (kv0 >> 6) & 1;
    const unsigned short* Kb = Ks[buf];
    unsigned short* Kn = Ks[buf ^ 1];
    // single barrier: implicit vmcnt(0) drain = wait for Ks[buf] staging
    // (issued one full iteration ago); also fences readers of Kn.
    __syncthreads();
    // V A-fragments for this tile — issued BEFORE next-tile stage so the
    // PV-side wait on them leaves the stage outstanding
    bf16x8 va[4][2];
#pragma unroll
    for (int db = 0; db < 4; db++)
#pragma unroll
      for (int ks = 0; ks < 2; ks++)
        va[db][ks] = *(const bf16x8*)&vt[vbase + (size_t)(db * 16 + l16) * SEQ +
                                         kv0 + ks * 32 + quad * 8];
    if (kv0 + 64 < SEQ) {
#pragma unroll
      for (int t = 0; t < 2; t++) {
        int rbase = wave * 16 + t * 8;
        const unsigned short* ga =
            &qkv[(tok0 + kv0 + 64 + rbase + srow) * qrow + H + h * HDIM + schunk * 8];
        __builtin_amdgcn_global_load_lds(
            (const __attribute__((address_space(1))) unsigned int*)ga,
            (__attribute__((address_space(3))) unsigned int*)(Kn + rbase * 64), 16, 0, 0);
      }
    }
    // per 32-kv half: S^T strips -> exp/pack -> partial drain -> PV
#pragma unroll
    for (int half = 0; half < 2; half++) {
#pragma unroll
      for (int nbl = 0; nbl < 2; nbl++) {
        int nb = half * 2 + nbl;
        int row = nb * 16 + l16;
        bf16x8 ka[2];
#pragma unroll
        for (int ks = 0; ks < 2; ks++) {
          int pc = (ks * 4 + quad) ^ (row & 7);
          ka[ks] = *(const bf16x8*)&Kb[row * 64 + pc * 8];
        }
        f32x4 st[2];
#pragma unroll
        for (int mb = 0; mb < 2; mb++) st[mb] = (f32x4){0.f, 0.f, 0.f, 0.f};
#pragma unroll
        for (int ks = 0; ks < 2; ks++)
#pragma unroll
          for (int mb = 0; mb < 2; mb++)
            st[mb] = __builtin_amdgcn_mfma_f32_16x16x32_bf16(ka[ks], qb[mb][ks], st[mb], 0, 0, 0);
#pragma unroll
        for (int mb = 0; mb < 2; mb++) {
          float p0 = __expf(st[mb][0] * 0.125f);
          float p1 = __expf(st[mb][1] * 0.125f);
          float p2 = __expf(st[mb][2] * 0.125f);
          float p3 = __expf(st[mb][3] * 0.125f);
          l_part[mb] += (p0 + p1) + (p2 + p3);
          bf16x4 pk = {(__bf16)p0, (__bf16)p1, (__bf16)p2, (__bf16)p3};
          *(bf16x4*)&Psw[(mb * 16 + l16) * LPs + nb * 16 + quad * 4] = pk;
        }
      }
      // drain our wave's Ps writes for this half (wave-private, no barrier)
      __asm__ volatile("s_waitcnt lgkmcnt(0)" ::: "memory");
      bf16x8 pb[2];
#pragma unroll
      for (int mb = 0; mb < 2; mb++)
        pb[mb] = *(const bf16x8*)&Psw[(mb * 16 + l16) * LPs + half * 32 + quad * 8];
#pragma unroll
      for (int db = 0; db < 4; db++)
#pragma unroll
        for (int mb = 0; mb < 2; mb++)
          o_acc[mb][db] = __builtin_amdgcn_mfma_f32_16x16x32_bf16(va[db][half], pb[mb],
                                                                  o_acc[mb][db], 0, 0, 0);
    }
  }
  // reduce l across the 4 quads; lane then holds inv-l for its own q = mb*16+l16
#pragma unroll
  for (int mb = 0; mb < 2; mb++) {
    l_part[mb] += __shfl_xor(l_part[mb], 16);
    l_part[mb] += __shfl_xor(l_part[mb], 32);
    l_part[mb] = 1.0f / l_part[mb];
  }
  // O^T C-layout: col q = mb*16+l16, rows d = db*16+quad*4+r (contig) -> 8B stores
#pragma unroll
  for (int mb = 0; mb < 2; mb++) {
#pragma unroll
    for (int db = 0; db < 4; db++) {
      ushort4v o;
#pragma unroll
      for (int r = 0; r < 4; r++) o[r] = f2bf(o_acc[mb][db][r] * l_part[mb]);
      *(ushort4v*)&attn_out[(tok0 + qblk + mb * 16 + l16) * H + h * HDIM +
                            db * 16 + quad * 4] = o;
    }
  }
}

extern "C" void kernel_launch(void* const* d_in, const int* in_sizes, int n_in,
                              void* d_out, int out_size, void* d_ws, size_t ws_size,
                              hipStream_t stream) {
  const float* x = (const float*)d_in[0];
  const float* ln1_g = (const float*)d_in[1];
  const float* ln1_b = (const float*)d_in[2];
  const float* qkv_w = (const float*)d_in[3];
  const float* qkv_b = (const float*)d_in[4];
  const float* out_w = (const float*)d_in[5];
  const float* out_b = (const float*)d_in[6];
  const float* ln2_g = (const float*)d_in[7];
  const float* ln2_b = (const float*)d_in[8];
  const float* w1 = (const float*)d_in[9];
  const float* b1 = (const float*)d_in[10];
  const float* w2 = (const float*)d_in[11];
  const float* b2 = (const float*)d_in[12];
  float* outp = (float*)d_out;

  size_t off = 0;
  auto take = [&](size_t n) {
    char* p = (char*)d_ws + off;
    off += (n + 255) & ~(size_t)255;
    return p;
  };
  unsigned short* h1 = (unsigned short*)take((size_t)NTOK * H * 2);       // also h2
  unsigned short* qkvb = (unsigned short*)take((size_t)NTOK * 3 * H * 2); // qkv; later mid
  unsigned short* attn = (unsigned short*)take((size_t)NTOK * H * 2);
  float* x1 = (float*)take((size_t)NTOK * H * 4);
  unsigned short* qkvwt = (unsigned short*)take((size_t)3 * H * H * 2);
  unsigned short* outwt = (unsigned short*)take((size_t)H * H * 2);
  unsigned short* w1t = (unsigned short*)take((size_t)H * IDIM * 2);
  unsigned short* w2t = (unsigned short*)take((size_t)H * IDIM * 2);
  unsigned short* h2 = h1;
  unsigned short* mid = qkvb;                // [NTOK][IDIM] aliases qkv+attn exactly
  unsigned short* vt = (unsigned short*)x1;  // vt dead before proj writes x1

  dim3 tb(32, 8);
  transpose_cast_kernel<<<dim3(3 * H / 32, H / 32), tb, 0, stream>>>(qkv_w, qkvwt, H, 3 * H);
  transpose_cast_kernel<<<dim3(H / 32, H / 32), tb, 0, stream>>>(out_w, outwt, H, H);
  transpose_cast_kernel<<<dim3(IDIM / 32, H / 32), tb, 0, stream>>>(w1, w1t, H, IDIM);
  transpose_cast_kernel<<<dim3(H / 32, IDIM / 32), tb, 0, stream>>>(w2, w2t, IDIM, H);

  layernorm_kernel<<<NTOK, 256, 0, stream>>>(x, ln1_g, ln1_b, h1);
  // QKV GEMM; v-slice blocks (n0>=2H) write vt transposed directly
  gemm_bt_kernel<0><<<dim3(3 * H / 128, NTOK / 128), 256, 0, stream>>>(
      h1, qkvwt, qkv_b, nullptr, qkvb, vt, NTOK, 3 * H, H);
  flash_attn_kernel<<<dim3(SEQ / 128, BATCH * NHEAD), 256, 0, stream>>>(qkvb, vt, attn);
  gemm_bt_kernel<2><<<dim3(H / 128, NTOK / 128), 256, 0, stream>>>(
      attn, outwt, out_b, x, x1, nullptr, NTOK, H, H);
  layernorm_kernel<<<NTOK, 256, 0, stream>>>(x1, ln2_g, ln2_b, h2);
  gemm_bt_kernel<1><<<dim3(IDIM / 128, NTOK / 128), 256, 0, stream>>>(
      h2, w1t, b1, nullptr, mid, nullptr, NTOK, IDIM, H);
  gemm_bt_kernel<2><<<dim3(H / 128, NTOK / 128), 256, 0, stream>>>(
      mid, w2t, b2, x1, outp, nullptr, NTOK, H, IDIM);
}

// Round 7
// 632.605 us; speedup vs baseline: 1.1008x; 1.0844x over previous
//
#include <hip/hip_runtime.h>
#include <math.h>

#define H 1024
#define NHEAD 16
#define HDIM 64
#define IDIM 4096
#define BATCH 4
#define SEQ 2048
#define NTOK 8192
#define LN_EPS 1e-5f

typedef __bf16 bf16x8 __attribute__((ext_vector_type(8)));
typedef __bf16 bf16x4 __attribute__((ext_vector_type(4)));
typedef float f32x4 __attribute__((ext_vector_type(4)));
typedef unsigned short ushort8 __attribute__((ext_vector_type(8)));
typedef unsigned short ushort4v __attribute__((ext_vector_type(4)));

__device__ __forceinline__ unsigned short f2bf(float f) {
  union { float f; unsigned int u; } v; v.f = f;
  unsigned int u = v.u;
  return (unsigned short)((u + 0x7FFFu + ((u >> 16) & 1u)) >> 16);
}

// ---------- transpose + cast: W[K][N] f32 -> Wt[N][K] bf16 ----------
__global__ void transpose_cast_kernel(const float* __restrict__ W,
                                      unsigned short* __restrict__ Wt,
                                      int K, int N) {
  __shared__ unsigned short tile[32][33];
  int n0 = blockIdx.x * 32, k0 = blockIdx.y * 32;
  int tx = threadIdx.x, ty = threadIdx.y;  // 32 x 8
#pragma unroll
  for (int i = 0; i < 4; i++) {
    int k = ty + i * 8;
    tile[tx][k] = f2bf(W[(size_t)(k0 + k) * N + n0 + tx]);
  }
  __syncthreads();
#pragma unroll
  for (int i = 0; i < 4; i++) {
    int n = ty + i * 8;
    Wt[(size_t)(n0 + n) * K + k0 + tx] = tile[n][tx];
  }
}

// ---------- layernorm: f32 [rows][H] -> bf16 ----------
__global__ __launch_bounds__(256)
void layernorm_kernel(const float* __restrict__ x, const float* __restrict__ g,
                      const float* __restrict__ b, unsigned short* __restrict__ out) {
  __shared__ float sb[4];
  int row = blockIdx.x;
  int tid = threadIdx.x;
  const float4* xr = (const float4*)(x + (size_t)row * H);
  float4 v = xr[tid];
  float s = v.x + v.y + v.z + v.w;
#pragma unroll
  for (int o = 32; o > 0; o >>= 1) s += __shfl_down(s, o);
  if ((tid & 63) == 0) sb[tid >> 6] = s;
  __syncthreads();
  float mu = (sb[0] + sb[1] + sb[2] + sb[3]) * (1.0f / H);
  __syncthreads();
  float dx = v.x - mu, dy = v.y - mu, dz = v.z - mu, dw = v.w - mu;
  float s2 = dx * dx + dy * dy + dz * dz + dw * dw;
#pragma unroll
  for (int o = 32; o > 0; o >>= 1) s2 += __shfl_down(s2, o);
  if ((tid & 63) == 0) sb[tid >> 6] = s2;
  __syncthreads();
  float var = (sb[0] + sb[1] + sb[2] + sb[3]) * (1.0f / H);
  float rs = rsqrtf(var + LN_EPS);
  float4 gv = ((const float4*)g)[tid];
  float4 bv = ((const float4*)b)[tid];
  ushort4v ov;
  ov[0] = f2bf(dx * rs * gv.x + bv.x);
  ov[1] = f2bf(dy * rs * gv.y + bv.y);
  ov[2] = f2bf(dz * rs * gv.z + bv.z);
  ov[3] = f2bf(dw * rs * gv.w + bv.w);
  ((ushort4v*)(out + (size_t)row * H))[tid] = ov;
}

// ---------- GEMM: C = A(bf16,[M][K]) @ Bt(bf16,[N][K])^T + bias ----------
// Single-barrier double-buffered K-loop: tile k+1's global_load_lds issued
// right after the barrier that publishes tile k; the NEXT iteration's barrier
// (implicit vmcnt(0) drain) is the wait -> staging gets a full compute phase
// in flight, and barrier count halves vs the 2-barrier m97 structure.
// MFMA computes C^T (lane owns row m=l16, reg r = 4 consecutive N cols).
// EPI 0: bf16 (opt fused V-transpose for QKV v-slice); 1: bf16 gelu; 2: f32+res.
template <int EPI>
__global__ __launch_bounds__(256)
void gemm_bt_kernel(const unsigned short* __restrict__ A,
                    const unsigned short* __restrict__ Bt,
                    const float* __restrict__ bias,
                    const float* __restrict__ res,
                    void* __restrict__ out, unsigned short* __restrict__ vt_out,
                    int M, int N, int K) {
  __shared__ __align__(16) unsigned short As[2][128 * 32];
  __shared__ __align__(16) unsigned short Bs[2][128 * 32];
  int tid = threadIdx.x;
  int wave = tid >> 6, lane = tid & 63;
  int quad = lane >> 4, l16 = lane & 15;
  int wm = wave >> 1, wn = wave & 1;
  int m0 = blockIdx.y * 128, n0 = blockIdx.x * 128;
  f32x4 acc[4][4];  // [i=m strip][j=n strip]; reg r = n offset (C^T layout)
#pragma unroll
  for (int i = 0; i < 4; i++)
#pragma unroll
    for (int j = 0; j < 4; j++) acc[i][j] = (f32x4){0.f, 0.f, 0.f, 0.f};

  int rl = (lane >> 2);
  int cphys = lane & 3;

  auto stage = [&](int k0, int sel) {
#pragma unroll
    for (int t = 0; t < 2; t++) {
      int ch = wave * 2 + t;
      int rloc = ch * 16 + rl;
      int clog = cphys ^ ((rloc >> 1) & 3);
      const unsigned short* ga = A + (size_t)(m0 + rloc) * K + k0 + clog * 8;
      __builtin_amdgcn_global_load_lds(
          (const __attribute__((address_space(1))) unsigned int*)ga,
          (__attribute__((address_space(3))) unsigned int*)(&As[sel][ch * 512]), 16, 0, 0);
      const unsigned short* gb = Bt + (size_t)(n0 + rloc) * K + k0 + clog * 8;
      __builtin_amdgcn_global_load_lds(
          (const __attribute__((address_space(1))) unsigned int*)gb,
          (__attribute__((address_space(3))) unsigned int*)(&Bs[sel][ch * 512]), 16, 0, 0);
    }
  };

  stage(0, 0);  // prologue
  for (int k0 = 0; k0 < K; k0 += 32) {
    int sel = (k0 >> 5) & 1;
    // single barrier: vmcnt(0) drain = wait for tile k0's staging (issued one
    // full iteration ago); lgkm drain = all waves done reading buf sel^1.
    __syncthreads();
    if (k0 + 32 < K) stage(k0 + 32, sel ^ 1);
    bf16x8 af[4], bfv[4];
#pragma unroll
    for (int i = 0; i < 4; i++) {
      int ra = wm * 64 + i * 16 + l16;
      af[i] = *(const bf16x8*)&As[sel][ra * 32 + ((quad ^ ((ra >> 1) & 3)) << 3)];
      int rb = wn * 64 + i * 16 + l16;
      bfv[i] = *(const bf16x8*)&Bs[sel][rb * 32 + ((quad ^ ((rb >> 1) & 3)) << 3)];
    }
#pragma unroll
    for (int i = 0; i < 4; i++)
#pragma unroll
      for (int j = 0; j < 4; j++)
        acc[i][j] = __builtin_amdgcn_mfma_f32_16x16x32_bf16(bfv[j], af[i], acc[i][j], 0, 0, 0);
  }
  // epilogue: lane = row m (l16), reg r = col n offset (quad*4+r)
  bool vslice = (EPI == 0) && (vt_out != nullptr) && (n0 >= 2 * H);
#pragma unroll
  for (int i = 0; i < 4; i++) {
    int m = m0 + wm * 64 + i * 16 + l16;
#pragma unroll
    for (int j = 0; j < 4; j++) {
      int nb = n0 + wn * 64 + j * 16 + quad * 4;
      float4 bv4 = *(const float4*)&bias[nb];
      float v0 = acc[i][j][0] + bv4.x;
      float v1 = acc[i][j][1] + bv4.y;
      float v2 = acc[i][j][2] + bv4.z;
      float v3 = acc[i][j][3] + bv4.w;
      size_t off = (size_t)m * N + nb;
      if (EPI == 0) {
        if (vslice) {
          // write vt[bh][d][s] transposed; skip the qkvb row write
          int bb = m >> 11, s = m & (SEQ - 1);
          int cb = nb - 2 * H;
          int hh = cb >> 6, dd = cb & 63;
          size_t base = ((size_t)(bb * NHEAD + hh) * HDIM + dd) * SEQ + s;
          vt_out[base] = f2bf(v0);
          vt_out[base + SEQ] = f2bf(v1);
          vt_out[base + 2 * SEQ] = f2bf(v2);
          vt_out[base + 3 * SEQ] = f2bf(v3);
        } else {
          bf16x4 pk = {(__bf16)v0, (__bf16)v1, (__bf16)v2, (__bf16)v3};
          *(bf16x4*)&((unsigned short*)out)[off] = pk;
        }
      } else if (EPI == 1) {
        float g0 = v0 / (1.f + __expf(-1.5957691216057308f * (v0 + 0.044715f * v0 * v0 * v0)));
        float g1 = v1 / (1.f + __expf(-1.5957691216057308f * (v1 + 0.044715f * v1 * v1 * v1)));
        float g2 = v2 / (1.f + __expf(-1.5957691216057308f * (v2 + 0.044715f * v2 * v2 * v2)));
        float g3 = v3 / (1.f + __expf(-1.5957691216057308f * (v3 + 0.044715f * v3 * v3 * v3)));
        bf16x4 pk = {(__bf16)g0, (__bf16)g1, (__bf16)g2, (__bf16)g3};
        *(bf16x4*)&((unsigned short*)out)[off] = pk;
      } else {
        float4 rv = *(const float4*)&res[off];
        float4 o4;
        o4.x = v0 + rv.x; o4.y = v1 + rv.y; o4.z = v2 + rv.z; o4.w = v3 + rv.w;
        *(float4*)&((float*)out)[off] = o4;
      }
    }
  }
}

// ---------- flash attention v7: v6 structure, slimmed LDS (6 blocks/CU) ----------
// Block = 4 waves, BQ=128 (wave owns 32 q), BKV=64, grid 1024 blocks.
// Ks double-buffered, single barrier per iter (implicit vmcnt(0) is the wait
// for the stage issued one iteration ago). va (V reg frags) issued before the
// stage. S^T = mfma(K_a, Q_b); P kv-contig -> packed ds_write_b64; PV per
// 32-kv half with partial lgkm drains. Max-free softmax (|s/8| << 88).
// LPs=40: bank mapping stays at the HW minimum (8/bank b128, 4/bank b64).
__global__ __launch_bounds__(256)
void flash_attn_kernel(const unsigned short* __restrict__ qkv,
                       const unsigned short* __restrict__ vt,
                       unsigned short* __restrict__ attn_out) {
  constexpr int LPs = 40;
  __shared__ __align__(16) unsigned short Ks[2][64 * 64];
  __shared__ __align__(16) unsigned short Ps[4 * 32 * LPs];
  int tid = threadIdx.x;
  int wave = tid >> 6, lane = tid & 63;
  int quad = lane >> 4, l16 = lane & 15;
  int bh = blockIdx.y, b = bh >> 4, h = bh & 15;
  int qblk = blockIdx.x * 128 + wave * 32;
  const size_t qrow = 3 * H;
  const size_t tok0 = (size_t)b * SEQ;
  const size_t vbase = (size_t)bh * HDIM * SEQ;
  unsigned short* Psw = Ps + wave * 32 * LPs;

  // Q B-fragments (q on l16), register-resident for the whole loop
  bf16x8 qb[2][2];
#pragma unroll
  for (int mb = 0; mb < 2; mb++)
#pragma unroll
    for (int ks = 0; ks < 2; ks++)
      qb[mb][ks] = *(const bf16x8*)&qkv[(tok0 + qblk + mb * 16 + l16) * qrow +
                                        h * HDIM + ks * 32 + quad * 8];

  float l_part[2] = {0.f, 0.f};
  f32x4 o_acc[2][4];  // [mb][db], O^T layout (rows d, cols q)
#pragma unroll
  for (int mb = 0; mb < 2; mb++)
#pragma unroll
    for (int db = 0; db < 4; db++) o_acc[mb][db] = (f32x4){0.f, 0.f, 0.f, 0.f};

  int srow = lane >> 3;            // 0..7: row within 8-row staging group
  int schunk = (lane & 7) ^ srow;  // swizzled 16B source chunk

  // prologue: stage tile 0 into buf 0
#pragma unroll
  for (int t = 0; t < 2; t++) {
    int rbase = wave * 16 + t * 8;
    const unsigned short* ga =
        &qkv[(tok0 + rbase + srow) * qrow + H + h * HDIM + schunk * 8];
    __builtin_amdgcn_global_load_lds(
        (const __attribute__((address_space(1))) unsigned int*)ga,
        (__attribute__((address_space(3))) unsigned int*)(&Ks[0][rbase * 64]), 16, 0, 0);
  }

  for (int kv0 = 0; kv0 < SEQ; kv0 += 64) {
    int buf = (kv0 >> 6) & 1;
    const unsigned short* Kb = Ks[buf];
    unsigned short* Kn = Ks[buf ^ 1];
    __syncthreads();  // vmcnt(0) drain = Ks[buf] staged; fences Kn readers
    // V A-fragments for this tile — issued BEFORE next-tile stage so the
    // PV-side wait on them leaves the stage outstanding
    bf16x8 va[4][2];
#pragma unroll
    for (int db = 0; db < 4; db++)
#pragma unroll
      for (int ks = 0; ks < 2; ks++)
        va[db][ks] = *(const bf16x8*)&vt[vbase + (size_t)(db * 16 + l16) * SEQ +
                                         kv0 + ks * 32 + quad * 8];
    if (kv0 + 64 < SEQ) {
#pragma unroll
      for (int t = 0; t < 2; t++) {
        int rbase = wave * 16 + t * 8;
        const unsigned short* ga =
            &qkv[(tok0 + kv0 + 64 + rbase + srow) * qrow + H + h * HDIM + schunk * 8];
        __builtin_amdgcn_global_load_lds(
            (const __attribute__((address_space(1))) unsigned int*)ga,
            (__attribute__((address_space(3))) unsigned int*)(Kn + rbase * 64), 16, 0, 0);
      }
    }
    // per 32-kv half: S^T strips -> exp/pack -> partial drain -> PV
#pragma unroll
    for (int half = 0; half < 2; half++) {
#pragma unroll
      for (int nbl = 0; nbl < 2; nbl++) {
        int nb = half * 2 + nbl;
        int row = nb * 16 + l16;
        bf16x8 ka[2];
#pragma unroll
        for (int ks = 0; ks < 2; ks++) {
          int pc = (ks * 4 + quad) ^ (row & 7);
          ka[ks] = *(const bf16x8*)&Kb[row * 64 + pc * 8];
        }
        f32x4 st[2];
#pragma unroll
        for (int mb = 0; mb < 2; mb++) st[mb] = (f32x4){0.f, 0.f, 0.f, 0.f};
#pragma unroll
        for (int ks = 0; ks < 2; ks++)
#pragma unroll
          for (int mb = 0; mb < 2; mb++)
            st[mb] = __builtin_amdgcn_mfma_f32_16x16x32_bf16(ka[ks], qb[mb][ks], st[mb], 0, 0, 0);
#pragma unroll
        for (int mb = 0; mb < 2; mb++) {
          float p0 = __expf(st[mb][0] * 0.125f);
          float p1 = __expf(st[mb][1] * 0.125f);
          float p2 = __expf(st[mb][2] * 0.125f);
          float p3 = __expf(st[mb][3] * 0.125f);
          l_part[mb] += (p0 + p1) + (p2 + p3);
          bf16x4 pk = {(__bf16)p0, (__bf16)p1, (__bf16)p2, (__bf16)p3};
          *(bf16x4*)&Psw[(mb * 16 + l16) * LPs + nb * 16 + quad * 4] = pk;
        }
      }
      // drain our wave's Ps writes for this half (wave-private, no barrier)
      __asm__ volatile("s_waitcnt lgkmcnt(0)" ::: "memory");
      bf16x8 pb[2];
#pragma unroll
      for (int mb = 0; mb < 2; mb++)
        pb[mb] = *(const bf16x8*)&Psw[(mb * 16 + l16) * LPs + half * 32 + quad * 8];
#pragma unroll
      for (int db = 0; db < 4; db++)
#pragma unroll
        for (int mb = 0; mb < 2; mb++)
          o_acc[mb][db] = __builtin_amdgcn_mfma_f32_16x16x32_bf16(va[db][half], pb[mb],
                                                                  o_acc[mb][db], 0, 0, 0);
    }
  }
  // reduce l across the 4 quads; lane then holds inv-l for its own q = mb*16+l16
#pragma unroll
  for (int mb = 0; mb < 2; mb++) {
    l_part[mb] += __shfl_xor(l_part[mb], 16);
    l_part[mb] += __shfl_xor(l_part[mb], 32);
    l_part[mb] = 1.0f / l_part[mb];
  }
  // O^T C-layout: col q = mb*16+l16, rows d = db*16+quad*4+r (contig) -> 8B stores
#pragma unroll
  for (int mb = 0; mb < 2; mb++) {
#pragma unroll
    for (int db = 0; db < 4; db++) {
      ushort4v o;
#pragma unroll
      for (int r = 0; r < 4; r++) o[r] = f2bf(o_acc[mb][db][r] * l_part[mb]);
      *(ushort4v*)&attn_out[(tok0 + qblk + mb * 16 + l16) * H + h * HDIM +
                            db * 16 + quad * 4] = o;
    }
  }
}

extern "C" void kernel_launch(void* const* d_in, const int* in_sizes, int n_in,
                              void* d_out, int out_size, void* d_ws, size_t ws_size,
                              hipStream_t stream) {
  const float* x = (const float*)d_in[0];
  const float* ln1_g = (const float*)d_in[1];
  const float* ln1_b = (const float*)d_in[2];
  const float* qkv_w = (const float*)d_in[3];
  const float* qkv_b = (const float*)d_in[4];
  const float* out_w = (const float*)d_in[5];
  const float* out_b = (const float*)d_in[6];
  const float* ln2_g = (const float*)d_in[7];
  const float* ln2_b = (const float*)d_in[8];
  const float* w1 = (const float*)d_in[9];
  const float* b1 = (const float*)d_in[10];
  const float* w2 = (const float*)d_in[11];
  const float* b2 = (const float*)d_in[12];
  float* outp = (float*)d_out;

  size_t off = 0;
  auto take = [&](size_t n) {
    char* p = (char*)d_ws + off;
    off += (n + 255) & ~(size_t)255;
    return p;
  };
  unsigned short* h1 = (unsigned short*)take((size_t)NTOK * H * 2);       // also h2
  unsigned short* qkvb = (unsigned short*)take((size_t)NTOK * 3 * H * 2); // qkv; later mid
  unsigned short* attn = (unsigned short*)take((size_t)NTOK * H * 2);
  float* x1 = (float*)take((size_t)NTOK * H * 4);
  unsigned short* qkvwt = (unsigned short*)take((size_t)3 * H * H * 2);
  unsigned short* outwt = (unsigned short*)take((size_t)H * H * 2);
  unsigned short* w1t = (unsigned short*)take((size_t)H * IDIM * 2);
  unsigned short* w2t = (unsigned short*)take((size_t)H * IDIM * 2);
  unsigned short* h2 = h1;
  unsigned short* mid = qkvb;                // [NTOK][IDIM] aliases qkv+attn exactly
  unsigned short* vt = (unsigned short*)x1;  // vt dead before proj writes x1

  dim3 tb(32, 8);
  transpose_cast_kernel<<<dim3(3 * H / 32, H / 32), tb, 0, stream>>>(qkv_w, qkvwt, H, 3 * H);
  transpose_cast_kernel<<<dim3(H / 32, H / 32), tb, 0, stream>>>(out_w, outwt, H, H);
  transpose_cast_kernel<<<dim3(IDIM / 32, H / 32), tb, 0, stream>>>(w1, w1t, H, IDIM);
  transpose_cast_kernel<<<dim3(H / 32, IDIM / 32), tb, 0, stream>>>(w2, w2t, IDIM, H);

  layernorm_kernel<<<NTOK, 256, 0, stream>>>(x, ln1_g, ln1_b, h1);
  // QKV GEMM; v-slice blocks (n0>=2H) write vt transposed directly
  gemm_bt_kernel<0><<<dim3(3 * H / 128, NTOK / 128), 256, 0, stream>>>(
      h1, qkvwt, qkv_b, nullptr, qkvb, vt, NTOK, 3 * H, H);
  flash_attn_kernel<<<dim3(SEQ / 128, BATCH * NHEAD), 256, 0, stream>>>(qkvb, vt, attn);
  gemm_bt_kernel<2><<<dim3(H / 128, NTOK / 128), 256, 0, stream>>>(
      attn, outwt, out_b, x, x1, nullptr, NTOK, H, H);
  layernorm_kernel<<<NTOK, 256, 0, stream>>>(x1, ln2_g, ln2_b, h2);
  gemm_bt_kernel<1><<<dim3(IDIM / 128, NTOK / 128), 256, 0, stream>>>(
      h2, w1t, b1, nullptr, mid, nullptr, NTOK, IDIM, H);
  gemm_bt_kernel<2><<<dim3(H / 128, NTOK / 128), 256, 0, stream>>>(
      mid, w2t, b2, x1, outp, nullptr, NTOK, H, IDIM);
}